// Round 1
// baseline (260.054 us; speedup 1.0000x reference)
//
#include <hip/hip_runtime.h>
#include <hip/hip_bf16.h>
#include <math.h>

typedef __attribute__((ext_vector_type(8))) short bf16x8;
typedef __attribute__((ext_vector_type(4))) float f32x4;

__device__ __forceinline__ float bf2f_bits(unsigned short u) {
    union { float f; unsigned int i; } x; x.i = ((unsigned int)u) << 16; return x.f;
}

// ---------------- qkv projection: q/k/v = X @ W + b (f32 out to ws) ----------
__global__ void qkv_proj_kernel(const float* __restrict__ query,
                                const float* __restrict__ key,
                                const float* __restrict__ value,
                                const float* __restrict__ Wq, const float* __restrict__ bq,
                                const float* __restrict__ Wk, const float* __restrict__ bk,
                                const float* __restrict__ Wv, const float* __restrict__ bv,
                                float* __restrict__ qf, float* __restrict__ kf,
                                float* __restrict__ vf)
{
    const int mat = blockIdx.x >> 8;   // 0:q 1:k 2:v
    const int rb  = blockIdx.x & 255;  // 16-row block of 4096 rows
    const float* X; const float* W; const float* bias; float* dst;
    if (mat == 0)      { X = query; W = Wq; bias = bq; dst = qf; }
    else if (mat == 1) { X = key;   W = Wk; bias = bk; dst = kf; }
    else               { X = value; W = Wv; bias = bv; dst = vf; }

    __shared__ float sX[16][128];
    const int tid = threadIdx.x;
    const float* src = X + (size_t)rb * 16 * 128;
    #pragma unroll
    for (int i = 0; i < 8; ++i) {
        int idx = tid + i * 256;
        sX[idx >> 7][idx & 127] = src[idx];
    }
    __syncthreads();

    const int col = tid & 127;
    const int rg  = tid >> 7;
    float acc[8] = {0.f,0.f,0.f,0.f,0.f,0.f,0.f,0.f};
    for (int e = 0; e < 128; ++e) {
        float w = W[e * 128 + col];
        #pragma unroll
        for (int r = 0; r < 8; ++r) acc[r] += sX[rg * 8 + r][e] * w;
    }
    float bb = bias[col];
    #pragma unroll
    for (int r = 0; r < 8; ++r)
        dst[(size_t)(rb * 16 + rg * 8 + r) * 128 + col] = acc[r] + bb;
}

// ---------------- fused main kernel: one workgroup per (b, n) ----------------
// per m-tile (64): stage rel_pe->bf16 LDS, MFMA project with Wpe, scores,
// online softmax, accumulate out += p*(v+pe); epilogue: out @ Wo + bo.
__global__ __launch_bounds__(256) void mha_main_kernel(
    const float* __restrict__ relpe,
    const float* __restrict__ mask,
    const float* __restrict__ qf,
    const float* __restrict__ kf,
    const float* __restrict__ vf,
    const float* __restrict__ Wpe, const float* __restrict__ bpe,
    const float* __restrict__ Wo,  const float* __restrict__ bo,
    float* __restrict__ out)
{
    __shared__ __hip_bfloat16 sW[128][136];   // Wpe^T  (sW[o][k] = Wpe[k][o]), bf16
    __shared__ __hip_bfloat16 sA[64][136];    // rel_pe tile (bf16), reused for pe tile
    __shared__ float sP[8][64];               // exp-scores p
    __shared__ float sQ[128];
    __shared__ float sBpe[128];
    __shared__ float sM[8], sL[8], sR[8];     // online softmax state
    __shared__ float sRed[128];
    __shared__ float sOut[128];

    const int tid  = threadIdx.x;
    const int lane = tid & 63;
    const int wv   = tid >> 6;
    const int b    = blockIdx.x >> 8;
    const int n    = blockIdx.x & 255;

    // ---- load Wpe^T as bf16 (coalesced read, transposed write)
    for (int i = 0; i < 64; ++i) {
        int idx = tid + i * 256;            // 16384 elems
        int k = idx >> 7, o = idx & 127;
        sW[o][k] = __float2bfloat16(Wpe[idx]);
    }
    if (tid < 128) {
        sQ[tid]   = qf[((size_t)(b * 256 + n)) * 128 + tid];
        sBpe[tid] = bpe[tid];
    }
    if (tid < 8) { sM[tid] = -INFINITY; sL[tid] = 0.f; }

    float out_acc = 0.f;
    const int e     = tid & 127;   // PV/epilogue column
    const int halfp = tid >> 7;    // PV m-half
    const int hh    = e >> 4;      // head of column e
    const int hsc   = tid >> 5;    // score-phase head
    const int ml    = tid & 31;    // score-phase m-lane
    __syncthreads();

    for (int t = 0; t < 4; ++t) {
        // ---- stage rel_pe tile (64x128 f32, fully contiguous) -> bf16 sA
        const float4* src4 =
            (const float4*)(relpe + (((size_t)(b * 256 + n)) * 256 + t * 64) * 128);
        #pragma unroll
        for (int i = 0; i < 8; ++i) {
            int idx4 = tid + i * 256;       // 2048 float4
            float4 v = src4[idx4];
            int lr = idx4 >> 5;
            int c4 = (idx4 & 31) * 4;
            __hip_bfloat162* dp = (__hip_bfloat162*)&sA[lr][c4];
            dp[0] = __float22bfloat162_rn(make_float2(v.x, v.y));
            dp[1] = __float22bfloat162_rn(make_float2(v.z, v.w));
        }
        __syncthreads();

        // ---- MFMA: pe(64x128) = A(64x128) @ Wpe(128x128), wave wv owns rows wv*16..+16
        f32x4 acc[8] = {};
        #pragma unroll
        for (int kt = 0; kt < 4; ++kt) {
            bf16x8 af = *(const bf16x8*)&sA[wv * 16 + (lane & 15)][kt * 32 + (lane >> 4) * 8];
            #pragma unroll
            for (int nt = 0; nt < 8; ++nt) {
                bf16x8 bfr = *(const bf16x8*)&sW[nt * 16 + (lane & 15)][kt * 32 + (lane >> 4) * 8];
                acc[nt] = __builtin_amdgcn_mfma_f32_16x16x32_bf16(af, bfr, acc[nt], 0, 0, 0);
            }
        }
        __syncthreads();   // all reads of sA done before overwrite

        // ---- write pe (+bpe) back into sA as bf16
        #pragma unroll
        for (int nt = 0; nt < 8; ++nt) {
            int ee = nt * 16 + (lane & 15);
            float bv_ = sBpe[ee];
            #pragma unroll
            for (int r = 0; r < 4; ++r) {
                int row = wv * 16 + (lane >> 4) * 4 + r;
                sA[row][ee] = __float2bfloat16(acc[nt][r] + bv_);
            }
        }
        __syncthreads();

        // ---- scores: thread (hsc, ml) does local rows ml and ml+32
        float sc[2];
        #pragma unroll
        for (int hf = 0; hf < 2; ++hf) {
            int lr = ml + hf * 32;
            const float4* k4 =
                (const float4*)(kf + ((size_t)(b * 256) + t * 64 + lr) * 128 + hsc * 16);
            float kvv[16];
            ((float4*)kvv)[0] = k4[0];
            ((float4*)kvv)[1] = k4[1];
            ((float4*)kvv)[2] = k4[2];
            ((float4*)kvv)[3] = k4[3];
            const bf16x8* p8 = (const bf16x8*)&sA[lr][hsc * 16];
            bf16x8 pa = p8[0], pb = p8[1];
            const float* qh = &sQ[hsc * 16];
            float s = 0.f;
            #pragma unroll
            for (int d = 0; d < 8; ++d)
                s += qh[d] * (kvv[d] + bf2f_bits((unsigned short)pa[d]));
            #pragma unroll
            for (int d = 0; d < 8; ++d)
                s += qh[8 + d] * (kvv[8 + d] + bf2f_bits((unsigned short)pb[d]));
            sc[hf] = s * 0.25f
                   + mask[(((size_t)(b * 256 + n)) * 256) + t * 64 + lr];
        }

        // ---- online softmax update (32-lane group per head)
        float tm = fmaxf(sc[0], sc[1]);
        #pragma unroll
        for (int msk = 16; msk >= 1; msk >>= 1)
            tm = fmaxf(tm, __shfl_xor(tm, msk, 32));
        float mold = sM[hsc];
        float mnew = fmaxf(mold, tm);
        float p0 = __expf(sc[0] - mnew);
        float p1 = __expf(sc[1] - mnew);
        float ts = p0 + p1;
        #pragma unroll
        for (int msk = 16; msk >= 1; msk >>= 1)
            ts += __shfl_xor(ts, msk, 32);
        if (ml == 0) {
            float rf = __expf(mold - mnew);
            sR[hsc] = rf;
            sM[hsc] = mnew;
            sL[hsc] = sL[hsc] * rf + ts;
        }
        sP[hsc][ml]      = p0;
        sP[hsc][ml + 32] = p1;
        __syncthreads();

        // ---- PV: out_acc(e, half) += sum_m p * (v + pe)
        out_acc *= sR[hh];
        const float* vp = vf + ((size_t)(b * 256) + t * 64 + halfp * 32) * 128 + e;
        #pragma unroll 8
        for (int mm = 0; mm < 32; ++mm) {
            int lr = halfp * 32 + mm;
            out_acc += sP[hh][lr] * (vp[(size_t)mm * 128] + __bfloat162float(sA[lr][e]));
        }
        __syncthreads();
    }

    // ---- combine halves, normalize
    if (halfp == 1) sRed[e] = out_acc;
    __syncthreads();
    if (halfp == 0) sOut[e] = (out_acc + sRed[e]) / sL[hh];
    __syncthreads();

    // ---- epilogue: y = out @ Wo + bo (halves split the e-sum)
    float y = 0.f;
    {
        const float* wo = Wo + (size_t)halfp * 64 * 128 + e;
        #pragma unroll 8
        for (int ee = 0; ee < 64; ++ee)
            y += sOut[halfp * 64 + ee] * wo[(size_t)ee * 128];
    }
    if (halfp == 1) sRed[e] = y;
    __syncthreads();
    if (halfp == 0)
        out[((size_t)(b * 256 + n)) * 128 + e] = y + sRed[e] + bo[e];
}

extern "C" void kernel_launch(void* const* d_in, const int* in_sizes, int n_in,
                              void* d_out, int out_size, void* d_ws, size_t ws_size,
                              hipStream_t stream)
{
    const float* query = (const float*)d_in[0];
    const float* key   = (const float*)d_in[1];
    const float* value = (const float*)d_in[2];
    const float* relpe = (const float*)d_in[3];
    const float* mask  = (const float*)d_in[4];
    const float* Wq  = (const float*)d_in[5];
    const float* bq  = (const float*)d_in[6];
    const float* Wk  = (const float*)d_in[7];
    const float* bk  = (const float*)d_in[8];
    const float* Wv  = (const float*)d_in[9];
    const float* bv  = (const float*)d_in[10];
    const float* Wpe = (const float*)d_in[11];
    const float* bpe = (const float*)d_in[12];
    const float* Wo  = (const float*)d_in[13];
    const float* bo  = (const float*)d_in[14];
    float* out = (float*)d_out;

    float* qf = (float*)d_ws;                  // 16*256*128 f32 = 2 MB
    float* kf = qf + 16 * 256 * 128;           // 2 MB
    float* vf = kf + 16 * 256 * 128;           // 2 MB   (total 6 MB of ws)

    qkv_proj_kernel<<<dim3(768), dim3(256), 0, stream>>>(
        query, key, value, Wq, bq, Wk, bk, Wv, bv, qf, kf, vf);
    mha_main_kernel<<<dim3(4096), dim3(256), 0, stream>>>(
        relpe, mask, qf, kf, vf, Wpe, bpe, Wo, bo, out);
}

// Round 2
// 214.304 us; speedup vs baseline: 1.2135x; 1.2135x over previous
//
#include <hip/hip_runtime.h>
#include <hip/hip_bf16.h>
#include <math.h>

typedef __attribute__((ext_vector_type(8))) short bf16x8;
typedef __attribute__((ext_vector_type(4))) float f32x4;

// ---------------- qkv projection: q/k/v = X @ W + b (f32 out to ws) ----------
__global__ void qkv_proj_kernel(const float* __restrict__ query,
                                const float* __restrict__ key,
                                const float* __restrict__ value,
                                const float* __restrict__ Wq, const float* __restrict__ bq,
                                const float* __restrict__ Wk, const float* __restrict__ bk,
                                const float* __restrict__ Wv, const float* __restrict__ bv,
                                float* __restrict__ qf, float* __restrict__ kf,
                                float* __restrict__ vf)
{
    const int mat = blockIdx.x >> 8;   // 0:q 1:k 2:v
    const int rb  = blockIdx.x & 255;  // 16-row block of 4096 rows
    const float* X; const float* W; const float* bias; float* dst;
    if (mat == 0)      { X = query; W = Wq; bias = bq; dst = qf; }
    else if (mat == 1) { X = key;   W = Wk; bias = bk; dst = kf; }
    else               { X = value; W = Wv; bias = bv; dst = vf; }

    __shared__ float sX[16][128];
    const int tid = threadIdx.x;
    const float* src = X + (size_t)rb * 16 * 128;
    #pragma unroll
    for (int i = 0; i < 8; ++i) {
        int idx = tid + i * 256;
        sX[idx >> 7][idx & 127] = src[idx];
    }
    __syncthreads();

    const int col = tid & 127;
    const int rg  = tid >> 7;
    float acc[8] = {0.f,0.f,0.f,0.f,0.f,0.f,0.f,0.f};
    for (int e = 0; e < 128; ++e) {
        float w = W[e * 128 + col];
        #pragma unroll
        for (int r = 0; r < 8; ++r) acc[r] += sX[rg * 8 + r][e] * w;
    }
    float bb = bias[col];
    #pragma unroll
    for (int r = 0; r < 8; ++r)
        dst[(size_t)(rb * 16 + rg * 8 + r) * 128 + col] = acc[r] + bb;
}

// ---------------- fused main kernel: one workgroup per (b, n) ----------------
// Algorithmic restructure: never materialize pe.
//   score_pe[m,h] = relpe[m,:] . Wtilde[:,h],  Wtilde = Wpe_hblock @ (q_h/SCALE)
//   out_pe[h,:]   = (sum_m P[m,h] relpe[m,:]) @ Wpe_hblock  (pr accumulated online)
// Per tile: GEMM1 (4 MFMA/wave) -> softmax (+ f32 q.k) -> GEMM2 pr accum + VALU PV.
// rel_pe tile prefetched into registers at loop top (T14) to keep HBM busy.
__global__ __launch_bounds__(256, 4) void mha_main_kernel(
    const float* __restrict__ relpe,
    const float* __restrict__ mask,
    const float* __restrict__ qf,
    const float* __restrict__ kf,
    const float* __restrict__ vf,
    const float* __restrict__ Wpe, const float* __restrict__ bpe,
    const float* __restrict__ Wo,  const float* __restrict__ bo,
    float* __restrict__ out)
{
    __shared__ __hip_bfloat16 sA[64][136];   // rel_pe tile bf16
    __shared__ __hip_bfloat16 sWt[16][136];  // sWt[h][e] = Wtilde[e][h] bf16
    __shared__ __hip_bfloat16 sPb[16][72];   // P bf16, [h][m]
    __shared__ float sSc[64][9];             // raw pe-scores per tile
    __shared__ float sPf[8][68];             // P f32, [h][m]
    __shared__ float sPr[8][132];            // pr (epilogue)
    __shared__ float sQs[128];               // q / SCALE
    __shared__ float sCb[8];                 // (q_h . bpe_h)/SCALE
    __shared__ float sM[8], sL[8];
    __shared__ float sRf[16];
    __shared__ float sRed[128];
    __shared__ float sOut[128];

    const int tid  = threadIdx.x;
    const int lane = tid & 63;
    const int wv   = tid >> 6;
    const int b    = blockIdx.x >> 8;
    const int n    = blockIdx.x & 255;
    const size_t bn = (size_t)(b * 256 + n);

    // ---- prefetch tile 0 into registers
    float4 pf[8];
    {
        const float4* s4 = (const float4*)(relpe + (bn * 256) * 128);
        #pragma unroll
        for (int i = 0; i < 8; ++i) pf[i] = s4[tid + i * 256];
    }

    if (tid < 128) sQs[tid] = qf[bn * 128 + tid] * 0.25f;
    if (tid < 8)  { sM[tid] = -INFINITY; sL[tid] = 0.f; }
    if (tid < 16) sRf[tid] = 1.f;
    if (tid < 72) {
        #pragma unroll
        for (int r = 8; r < 16; ++r) sPb[r][tid] = __float2bfloat16(0.f);
    }
    __syncthreads();

    // ---- Wtilde[e][h] = sum_d Wpe[e][h*16+d] * qs[h*16+d]  (stored transposed)
    #pragma unroll
    for (int o = tid; o < 1024; o += 256) {
        int h = o >> 7, e = o & 127;
        const float4* wr = (const float4*)(Wpe + (size_t)e * 128 + h * 16);
        float4 w0 = wr[0], w1 = wr[1], w2 = wr[2], w3 = wr[3];
        const float* qh = &sQs[h * 16];
        float acc = w0.x*qh[0]+w0.y*qh[1]+w0.z*qh[2]+w0.w*qh[3]
                  + w1.x*qh[4]+w1.y*qh[5]+w1.z*qh[6]+w1.w*qh[7]
                  + w2.x*qh[8]+w2.y*qh[9]+w2.z*qh[10]+w2.w*qh[11]
                  + w3.x*qh[12]+w3.y*qh[13]+w3.z*qh[14]+w3.w*qh[15];
        sWt[h][e] = __float2bfloat16(acc);
    }
    if (tid < 128) {
        #pragma unroll
        for (int r = 8; r < 16; ++r) sWt[r][tid] = __float2bfloat16(0.f);
    }
    if (tid < 8) {
        float acc = 0.f;
        #pragma unroll
        for (int d = 0; d < 16; ++d) acc += bpe[tid * 16 + d] * sQs[tid * 16 + d];
        sCb[tid] = acc;
    }

    // ---- write tile 0 to sA (bf16)
    #pragma unroll
    for (int i = 0; i < 8; ++i) {
        int idx4 = tid + i * 256;
        int lr = idx4 >> 5, c4 = (idx4 & 31) * 4;
        __hip_bfloat162* dp = (__hip_bfloat162*)&sA[lr][c4];
        dp[0] = __float22bfloat162_rn(make_float2(pf[i].x, pf[i].y));
        dp[1] = __float22bfloat162_rn(make_float2(pf[i].z, pf[i].w));
    }
    __syncthreads();

    float out_acc = 0.f;
    f32x4 pr0 = {}, pr1 = {};
    const int e     = tid & 127;
    const int halfp = tid >> 7;
    const int hh    = e >> 4;
    const int hsc   = tid >> 5;
    const int ml    = tid & 31;
    const int arow  = lane & 15;
    const int koff  = lane >> 4;

    for (int t = 0; t < 4; ++t) {
        // issue next tile's global loads (stay in flight across all compute)
        if (t < 3) {
            const float4* s4 = (const float4*)(relpe + (bn * 256 + (t + 1) * 64) * 128);
            #pragma unroll
            for (int i = 0; i < 8; ++i) pf[i] = s4[tid + i * 256];
        }

        // ---- GEMM1: s_pe(64x16) = relpe_tile(64x128) @ Wtilde(128x16)
        f32x4 cs = {};
        #pragma unroll
        for (int kt = 0; kt < 4; ++kt) {
            bf16x8 af  = *(const bf16x8*)&sA[wv * 16 + arow][kt * 32 + koff * 8];
            bf16x8 bfr = *(const bf16x8*)&sWt[arow][kt * 32 + koff * 8];
            cs = __builtin_amdgcn_mfma_f32_16x16x32_bf16(af, bfr, cs, 0, 0, 0);
        }
        if (arow < 8) {
            #pragma unroll
            for (int r = 0; r < 4; ++r) sSc[wv * 16 + koff * 4 + r][arow] = cs[r];
        }
        __syncthreads();

        // ---- softmax: add f32 q.k, online update
        {
            float sc[2];
            #pragma unroll
            for (int hf = 0; hf < 2; ++hf) {
                int lr = ml + hf * 32;
                const float4* k4 =
                    (const float4*)(kf + ((size_t)(b * 256) + t * 64 + lr) * 128 + hsc * 16);
                float4 ka = k4[0], kb = k4[1], kc = k4[2], kd = k4[3];
                const float* qh = &sQs[hsc * 16];
                float s = sSc[lr][hsc] + sCb[hsc];
                s += ka.x*qh[0]+ka.y*qh[1]+ka.z*qh[2]+ka.w*qh[3]
                   + kb.x*qh[4]+kb.y*qh[5]+kb.z*qh[6]+kb.w*qh[7]
                   + kc.x*qh[8]+kc.y*qh[9]+kc.z*qh[10]+kc.w*qh[11]
                   + kd.x*qh[12]+kd.y*qh[13]+kd.z*qh[14]+kd.w*qh[15];
                sc[hf] = s + mask[bn * 256 + t * 64 + lr];
            }
            float tm = fmaxf(sc[0], sc[1]);
            #pragma unroll
            for (int m2 = 16; m2 >= 1; m2 >>= 1) tm = fmaxf(tm, __shfl_xor(tm, m2, 32));
            float mold = sM[hsc];
            float mnew = fmaxf(mold, tm);
            float p0 = __expf(sc[0] - mnew), p1 = __expf(sc[1] - mnew);
            float ts = p0 + p1;
            #pragma unroll
            for (int m2 = 16; m2 >= 1; m2 >>= 1) ts += __shfl_xor(ts, m2, 32);
            if (ml == 0) {
                float rf = __expf(mold - mnew);
                sRf[hsc] = rf;
                sM[hsc]  = mnew;
                sL[hsc]  = sL[hsc] * rf + ts;
            }
            sPf[hsc][ml]      = p0;
            sPf[hsc][ml + 32] = p1;
            sPb[hsc][ml]      = __float2bfloat16(p0);
            sPb[hsc][ml + 32] = __float2bfloat16(p1);
        }
        __syncthreads();

        // ---- GEMM2: pr += P^T(16x64) @ relpe_tile(64x128); VALU PV for v
        {
            #pragma unroll
            for (int r = 0; r < 4; ++r) {
                float rf = sRf[koff * 4 + r];
                pr0[r] *= rf; pr1[r] *= rf;
            }
            #pragma unroll
            for (int kt = 0; kt < 2; ++kt) {
                bf16x8 ap = *(const bf16x8*)&sPb[arow][kt * 32 + koff * 8];
                bf16x8 b0, b1;
                #pragma unroll
                for (int j = 0; j < 8; ++j) {
                    int row = kt * 32 + koff * 8 + j;
                    b0[j] = *(const short*)&sA[row][wv * 32 + arow];
                    b1[j] = *(const short*)&sA[row][wv * 32 + 16 + arow];
                }
                pr0 = __builtin_amdgcn_mfma_f32_16x16x32_bf16(ap, b0, pr0, 0, 0, 0);
                pr1 = __builtin_amdgcn_mfma_f32_16x16x32_bf16(ap, b1, pr1, 0, 0, 0);
            }
            out_acc *= sRf[hh];
            const float* vp = vf + ((size_t)(b * 256) + t * 64 + halfp * 32) * 128 + e;
            const float* pp = &sPf[hh][halfp * 32];
            #pragma unroll 8
            for (int mm = 0; mm < 32; ++mm)
                out_acc += pp[mm] * vp[(size_t)mm * 128];
        }
        __syncthreads();   // all sA reads done

        if (t < 3) {
            #pragma unroll
            for (int i = 0; i < 8; ++i) {
                int idx4 = tid + i * 256;
                int lr = idx4 >> 5, c4 = (idx4 & 31) * 4;
                __hip_bfloat162* dp = (__hip_bfloat162*)&sA[lr][c4];
                dp[0] = __float22bfloat162_rn(make_float2(pf[i].x, pf[i].y));
                dp[1] = __float22bfloat162_rn(make_float2(pf[i].z, pf[i].w));
            }
            __syncthreads();
        }
    }

    // ---- epilogue
    if (halfp) sRed[e] = out_acc;
    __syncthreads();
    float outv = out_acc + (halfp ? 0.f : sRed[e]);   // valid for halfp==0

    #pragma unroll
    for (int r = 0; r < 4; ++r) {
        int row = koff * 4 + r;
        if (row < 8) {
            sPr[row][wv * 32 + arow]      = pr0[r];
            sPr[row][wv * 32 + 16 + arow] = pr1[r];
        }
    }
    __syncthreads();

    // out_pe partial: sum over half the e-range
    float ype = 0.f;
    {
        const float* wp  = Wpe + (size_t)(halfp * 64) * 128 + e;
        const float* prh = &sPr[hh][halfp * 64];
        #pragma unroll 8
        for (int ee = 0; ee < 64; ++ee) ype += prh[ee] * wp[(size_t)ee * 128];
    }
    if (halfp) sRed[e] = ype;
    __syncthreads();
    if (!halfp) sOut[e] = (outv + ype + sRed[e]) / sL[hh] + bpe[e];
    __syncthreads();

    // ---- y = out @ Wo + bo
    float y = 0.f;
    {
        const float* wo = Wo + (size_t)(halfp * 64) * 128 + e;
        #pragma unroll 8
        for (int ee = 0; ee < 64; ++ee) y += sOut[halfp * 64 + ee] * wo[(size_t)ee * 128];
    }
    if (halfp) sRed[e] = y;
    __syncthreads();
    if (!halfp) out[bn * 128 + e] = y + sRed[e] + bo[e];
}

extern "C" void kernel_launch(void* const* d_in, const int* in_sizes, int n_in,
                              void* d_out, int out_size, void* d_ws, size_t ws_size,
                              hipStream_t stream)
{
    const float* query = (const float*)d_in[0];
    const float* key   = (const float*)d_in[1];
    const float* value = (const float*)d_in[2];
    const float* relpe = (const float*)d_in[3];
    const float* mask  = (const float*)d_in[4];
    const float* Wq  = (const float*)d_in[5];
    const float* bq  = (const float*)d_in[6];
    const float* Wk  = (const float*)d_in[7];
    const float* bk  = (const float*)d_in[8];
    const float* Wv  = (const float*)d_in[9];
    const float* bv  = (const float*)d_in[10];
    const float* Wpe = (const float*)d_in[11];
    const float* bpe = (const float*)d_in[12];
    const float* Wo  = (const float*)d_in[13];
    const float* bo  = (const float*)d_in[14];
    float* out = (float*)d_out;

    float* qf = (float*)d_ws;                  // 2 MB
    float* kf = qf + 16 * 256 * 128;           // 2 MB
    float* vf = kf + 16 * 256 * 128;           // 2 MB

    qkv_proj_kernel<<<dim3(768), dim3(256), 0, stream>>>(
        query, key, value, Wq, bq, Wk, bk, Wv, bv, qf, kf, vf);
    mha_main_kernel<<<dim3(4096), dim3(256), 0, stream>>>(
        relpe, mask, qf, kf, vf, Wpe, bpe, Wo, bo, out);
}